// Round 23
// baseline (234.771 us; speedup 1.0000x reference)
//
#include <hip/hip_runtime.h>
#include <hip/hip_bf16.h>

// Windowed MHA, B=16 C=128 H=W=128, WINDOW=64, heads=4, d=32.
// R23 = R20 on a REGISTER DIET targeting the <=128-regs/wave occupancy tier
// (regs tier 129-256 -> 2 waves/SIMD; <=128 -> 4 waves/SIMD; AGPR accumulators
// share the budget but are invisible in rocprof VGPR_Count — R20 true total
// ~170 explains the stuck ~2 blocks/CU in every prior round).
//  - projections SEQUENTIAL (K, Q, V): one 32-reg accumulator live at a time
//  - attention in token-halves: sc/pP/o halved
//  - launch_bounds(256,4): cap 128, audited need ~116.
// All numerics byte-identical R20 (absmax-proven).

typedef __attribute__((ext_vector_type(8))) short bf16x8;
typedef __attribute__((ext_vector_type(4))) short bf16x4;
typedef __attribute__((ext_vector_type(4))) float f32x4;

#define MFMA32(A, B, C) __builtin_amdgcn_mfma_f32_16x16x32_bf16((A), (B), (C), 0, 0, 0)
#define MFMA16(A, B, C) __builtin_amdgcn_mfma_f32_16x16x16bf16_1k((A), (B), (C), 0, 0, 0)

__device__ __forceinline__ ushort f2bf(float f) {
    __hip_bfloat16 h = __float2bfloat16(f);       // RNE
    ushort u; __builtin_memcpy(&u, &h, 2); return u;
}
__device__ __forceinline__ unsigned pk2(float a, float b) {
    __hip_bfloat162 h = __float22bfloat162_rn(make_float2(a, b));  // lo=a, hi=b
    unsigned u; __builtin_memcpy(&u, &h, 4); return u;
}
__device__ __forceinline__ bf16x4 pk4(float a, float b, float c, float d) {
    uint2 u; u.x = pk2(a, b); u.y = pk2(c, d);
    bf16x4 r; __builtin_memcpy(&r, &u, 8); return r;
}
// 256B-row tile (sX): row bits 0-3 ^ bits 4-5 -> byte bits 4-7.
__device__ __forceinline__ int fsw(int row) { return ((row ^ (row >> 4)) & 15) << 4; }

__global__ void wconv(const float* __restrict__ Wq, const float* __restrict__ Wk,
                      const float* __restrict__ Wv, ushort* __restrict__ out) {
    int i = blockIdx.x * 256 + threadIdx.x;        // 16384 per matrix
    out[i]         = f2bf(Wq[i]);
    out[16384 + i] = f2bf(Wk[i]);
    out[32768 + i] = f2bf(Wv[i]);
}

__global__ __launch_bounds__(256, 4)
void attn_win(const float* __restrict__ x, const ushort* __restrict__ wbf,
              const float* __restrict__ bq, const float* __restrict__ bk,
              const float* __restrict__ bv, const float* __restrict__ Bb,
              float* __restrict__ out) {
    __shared__ __align__(16) char sX[16384];   // the ONLY LDS tenant

    const int tid = threadIdx.x;
    const int w = tid >> 6;          // wave = head (0..3)
    const int l = tid & 63;
    const int lr = l & 15;
    const int lg = (l >> 4) & 3;
    const int blk = blockIdx.x;
    const int b = blk >> 8, n = blk & 255;
    const long xbase = (long)b * 128 * 16384 + n * 64;

    // ---- stage X: 4-channel quads -> packed uint2 ds_writes (2 per thread) ----
    #pragma unroll
    for (int it = 0; it < 2; ++it) {
        int idx = it * 256 + tid;            // 512 items: 32 cq x 16 t4
        int cq = idx >> 4, t4 = idx & 15;
        const float* px = x + xbase + (long)(4 * cq) * 16384 + t4 * 4;
        float4 v0 = *(const float4*)(px);
        float4 v1 = *(const float4*)(px + 16384);
        float4 v2 = *(const float4*)(px + 32768);
        float4 v3 = *(const float4*)(px + 49152);
        float a0[4] = {v0.x, v0.y, v0.z, v0.w};
        float a1[4] = {v1.x, v1.y, v1.z, v1.w};
        float a2[4] = {v2.x, v2.y, v2.z, v2.w};
        float a3[4] = {v3.x, v3.y, v3.z, v3.w};
        #pragma unroll
        for (int jj = 0; jj < 4; ++jj) {
            int t = t4 * 4 + jj;
            uint2 pk;
            pk.x = pk2(a0[jj], a1[jj]);
            pk.y = pk2(a2[jj], a3[jj]);
            *(uint2*)(sX + t * 256 + ((8 * cq) ^ fsw(t))) = pk;
        }
    }
    __syncthreads();   // THE ONLY BARRIER

    // ---- SEQUENTIAL projections, K=32 MFMA, one accumulator at a time ----
    bf16x4 fQ[4][2], fK[4][2], fV[4][2];

    // K projection (W.X^T): D[och 4lg+r][tok lr]
    #pragma unroll 1
    for (int p = 0; p < 2; ++p) {
        const ushort* wp = wbf + (p == 0 ? 16384 : 0);
        const float* bias_p = (p == 0) ? bk : bq;
        f32x4 acc[2][4];   // [tn][tm]
        #pragma unroll
        for (int tn = 0; tn < 2; ++tn) {
            float4 bb = *(const float4*)(bias_p + 32 * w + 16 * tn + 4 * lg);
            #pragma unroll
            for (int tm = 0; tm < 4; ++tm)
                acc[tn][tm] = (f32x4){bb.x, bb.y, bb.z, bb.w};
        }
        #pragma unroll
        for (int kk = 0; kk < 4; ++kk) {
            bf16x8 aXk[4];
            #pragma unroll
            for (int tm = 0; tm < 4; ++tm) {
                int row = 16 * tm + lr;
                aXk[tm] = *(const bf16x8*)(sX + row * 256
                              + (((8 * lg + 32 * kk) * 2) ^ fsw(row)));
            }
            bf16x8 bW[2];
            #pragma unroll
            for (int tn = 0; tn < 2; ++tn)
                bW[tn] = *(const bf16x8*)(wp + (32 * w + 16 * tn + lr) * 128 + 8 * lg + 32 * kk);
            #pragma unroll
            for (int tn = 0; tn < 2; ++tn)
                #pragma unroll
                for (int tm = 0; tm < 4; ++tm)
                    acc[tn][tm] = MFMA32(bW[tn], aXk[tm], acc[tn][tm]);
        }
        #pragma unroll
        for (int tm = 0; tm < 4; ++tm)
            #pragma unroll
            for (int tn = 0; tn < 2; ++tn) {
                bf16x4 f = pk4(acc[tn][tm][0], acc[tn][tm][1],
                               acc[tn][tm][2], acc[tn][tm][3]);
                if (p == 0) fK[tm][tn] = f; else fQ[tm][tn] = f;
            }
    }

    // V projection (X.W^T): D[tok 4lg+r][och lr] -> PV B-fragments
    {
        const ushort* wp = wbf + 32768;
        f32x4 acc[4][2];
        #pragma unroll
        for (int tn = 0; tn < 2; ++tn) {
            float bias = bv[32 * w + 16 * tn + lr];
            #pragma unroll
            for (int tmi = 0; tmi < 4; ++tmi)
                acc[tmi][tn] = (f32x4){bias, bias, bias, bias};
        }
        #pragma unroll
        for (int kk = 0; kk < 4; ++kk) {
            bf16x8 aXk[4];
            #pragma unroll
            for (int tmi = 0; tmi < 4; ++tmi) {
                int row = 16 * tmi + lr;
                aXk[tmi] = *(const bf16x8*)(sX + row * 256
                               + (((8 * lg + 32 * kk) * 2) ^ fsw(row)));
            }
            bf16x8 bW[2];
            #pragma unroll
            for (int tn = 0; tn < 2; ++tn)
                bW[tn] = *(const bf16x8*)(wp + (32 * w + 16 * tn + lr) * 128 + 8 * lg + 32 * kk);
            #pragma unroll
            for (int tmi = 0; tmi < 4; ++tmi)
                #pragma unroll
                for (int tn = 0; tn < 2; ++tn)
                    acc[tmi][tn] = MFMA32(aXk[tmi], bW[tn], acc[tmi][tn]);
        }
        #pragma unroll
        for (int tmi = 0; tmi < 4; ++tmi)
            #pragma unroll
            for (int tn = 0; tn < 2; ++tn)
                fV[tmi][tn] = pk4(acc[tmi][tn][0], acc[tmi][tn][1],
                                  acc[tmi][tn][2], acc[tmi][tn][3]);
    }

    // ---- attention in TOKEN-HALVES: per half, 2 q-tiles -> sc/pP/o halved ----
    const float scale = 0.17677669529663687f;   // 1/sqrt(32)
    const float L2E = 1.4426950408889634f;
    #pragma unroll 1
    for (int h2 = 0; h2 < 2; ++h2) {
        bf16x4 pPh[4][2];   // [tmK][tmq within half]
        #pragma unroll
        for (int t2 = 0; t2 < 2; ++t2) {
            int tmQ = 2 * h2 + t2;
            f32x4 sc[4];
            #pragma unroll
            for (int tmK = 0; tmK < 4; ++tmK) {
                sc[tmK] = (f32x4){0.f, 0.f, 0.f, 0.f};
                sc[tmK] = MFMA16(fK[tmK][0], fQ[tmQ][0], sc[tmK]);
                sc[tmK] = MFMA16(fK[tmK][1], fQ[tmQ][1], sc[tmK]);
            }
            int q = 16 * tmQ + lr;
            float s = 0.f;
            #pragma unroll
            for (int tmK = 0; tmK < 4; ++tmK) {
                float4 bb = *(const float4*)(Bb + q * 64 + 16 * tmK + 4 * lg);
                float e0 = exp2f((sc[tmK][0] * scale + bb.x) * L2E);
                float e1 = exp2f((sc[tmK][1] * scale + bb.y) * L2E);
                float e2 = exp2f((sc[tmK][2] * scale + bb.z) * L2E);
                float e3 = exp2f((sc[tmK][3] * scale + bb.w) * L2E);
                sc[tmK][0] = e0; sc[tmK][1] = e1;
                sc[tmK][2] = e2; sc[tmK][3] = e3;
                s += (e0 + e1) + (e2 + e3);
            }
            s += __shfl_xor(s, 16);
            s += __shfl_xor(s, 32);
            float rs = 1.0f / s;
            #pragma unroll
            for (int tmK = 0; tmK < 4; ++tmK)
                pPh[tmK][t2] = pk4(sc[tmK][0] * rs, sc[tmK][1] * rs,
                                   sc[tmK][2] * rs, sc[tmK][3] * rs);
        }

        f32x4 o[2][2];
        #pragma unroll
        for (int t2 = 0; t2 < 2; ++t2)
            #pragma unroll
            for (int tn = 0; tn < 2; ++tn)
                o[t2][tn] = (f32x4){0.f, 0.f, 0.f, 0.f};
        #pragma unroll
        for (int tmK = 0; tmK < 4; ++tmK)
            #pragma unroll
            for (int t2 = 0; t2 < 2; ++t2)
                #pragma unroll
                for (int tn = 0; tn < 2; ++tn)
                    o[t2][tn] = MFMA16(pPh[tmK][t2], fV[tmK][tn], o[t2][tn]);

        #pragma unroll
        for (int t2 = 0; t2 < 2; ++t2)
            #pragma unroll
            for (int tn = 0; tn < 2; ++tn) {
                int ch = 32 * w + 16 * tn + lr;
                int tok = 16 * (2 * h2 + t2) + 4 * lg;
                float4 ov;
                ov.x = o[t2][tn][0];
                ov.y = o[t2][tn][1];
                ov.z = o[t2][tn][2];
                ov.w = o[t2][tn][3];
                *(float4*)(out + xbase + (long)ch * 16384 + tok) = ov;
            }
    }
}

extern "C" void kernel_launch(void* const* d_in, const int* in_sizes, int n_in,
                              void* d_out, int out_size, void* d_ws, size_t ws_size,
                              hipStream_t stream) {
    const float* x  = (const float*)d_in[0];
    const float* Wq = (const float*)d_in[1];
    const float* bq = (const float*)d_in[2];
    const float* Wk = (const float*)d_in[3];
    const float* bk = (const float*)d_in[4];
    const float* Wv = (const float*)d_in[5];
    const float* bv = (const float*)d_in[6];
    const float* Bb = (const float*)d_in[7];
    float* out = (float*)d_out;
    ushort* wbf = (ushort*)d_ws;   // 3 x 128x128 bf16 = 96 KB

    wconv<<<64, 256, 0, stream>>>(Wq, Wk, Wv, wbf);
    attn_win<<<4096, 256, 0, stream>>>(x, wbf, bq, bk, bv, Bb, out);
}

// Round 25
// 181.054 us; speedup vs baseline: 1.2967x; 1.2967x over previous
//
#include <hip/hip_runtime.h>
#include <hip/hip_bf16.h>

// Windowed MHA, B=16 C=128 H=W=128, WINDOW=64, heads=4, d=32.
// R25 = R24 register diet with R18-exact numerics restored:
//  per-tmQ column: compute all 4 sc tiles (16 f32), reduce s, then
//  NORMALIZE-BEFORE-PACK (pk4(sc*rs), abs err ~3e-5 vs 4e-3 unnormalized
//  -- R24's failure) and feed PV per tmK immediately.
//  - sequential projections (K,Q; V in two och-half passes)
//  - natural register peak ~95 (target <=128 tier / 4 waves/SIMD);
//    launch_bounds(256,2) -- NO cap squeezing (4 collapses on record).
// One wave = one (window, head); 4096 x 256thr; ONE barrier; K=32 projections,
// K=16 attention consuming D-layouts directly (R18/R20-proven).

typedef __attribute__((ext_vector_type(8))) short bf16x8;
typedef __attribute__((ext_vector_type(4))) short bf16x4;
typedef __attribute__((ext_vector_type(4))) float f32x4;

#define MFMA32(A, B, C) __builtin_amdgcn_mfma_f32_16x16x32_bf16((A), (B), (C), 0, 0, 0)
#define MFMA16(A, B, C) __builtin_amdgcn_mfma_f32_16x16x16bf16_1k((A), (B), (C), 0, 0, 0)

__device__ __forceinline__ ushort f2bf(float f) {
    __hip_bfloat16 h = __float2bfloat16(f);       // RNE
    ushort u; __builtin_memcpy(&u, &h, 2); return u;
}
__device__ __forceinline__ unsigned pk2(float a, float b) {
    __hip_bfloat162 h = __float22bfloat162_rn(make_float2(a, b));  // lo=a, hi=b
    unsigned u; __builtin_memcpy(&u, &h, 4); return u;
}
__device__ __forceinline__ bf16x4 pk4(float a, float b, float c, float d) {
    uint2 u; u.x = pk2(a, b); u.y = pk2(c, d);
    bf16x4 r; __builtin_memcpy(&r, &u, 8); return r;
}
// 256B-row tile (sX): row bits 0-3 ^ bits 4-5 -> byte bits 4-7.
__device__ __forceinline__ int fsw(int row) { return ((row ^ (row >> 4)) & 15) << 4; }

__global__ void wconv(const float* __restrict__ Wq, const float* __restrict__ Wk,
                      const float* __restrict__ Wv, ushort* __restrict__ out) {
    int i = blockIdx.x * 256 + threadIdx.x;        // 16384 per matrix
    out[i]         = f2bf(Wq[i]);
    out[16384 + i] = f2bf(Wk[i]);
    out[32768 + i] = f2bf(Wv[i]);
}

__global__ __launch_bounds__(256, 2)
void attn_win(const float* __restrict__ x, const ushort* __restrict__ wbf,
              const float* __restrict__ bq, const float* __restrict__ bk,
              const float* __restrict__ bv, const float* __restrict__ Bb,
              float* __restrict__ out) {
    __shared__ __align__(16) char sX[16384];   // the ONLY LDS tenant

    const int tid = threadIdx.x;
    const int w = tid >> 6;          // wave = head (0..3)
    const int l = tid & 63;
    const int lr = l & 15;
    const int lg = (l >> 4) & 3;
    const int blk = blockIdx.x;
    const int b = blk >> 8, n = blk & 255;
    const long xbase = (long)b * 128 * 16384 + n * 64;

    // ---- stage X: 4-channel quads -> packed uint2 ds_writes (2 per thread) ----
    #pragma unroll
    for (int it = 0; it < 2; ++it) {
        int idx = it * 256 + tid;            // 512 items: 32 cq x 16 t4
        int cq = idx >> 4, t4 = idx & 15;
        const float* px = x + xbase + (long)(4 * cq) * 16384 + t4 * 4;
        float4 v0 = *(const float4*)(px);
        float4 v1 = *(const float4*)(px + 16384);
        float4 v2 = *(const float4*)(px + 32768);
        float4 v3 = *(const float4*)(px + 49152);
        float a0[4] = {v0.x, v0.y, v0.z, v0.w};
        float a1[4] = {v1.x, v1.y, v1.z, v1.w};
        float a2[4] = {v2.x, v2.y, v2.z, v2.w};
        float a3[4] = {v3.x, v3.y, v3.z, v3.w};
        #pragma unroll
        for (int jj = 0; jj < 4; ++jj) {
            int t = t4 * 4 + jj;
            uint2 pk;
            pk.x = pk2(a0[jj], a1[jj]);
            pk.y = pk2(a2[jj], a3[jj]);
            *(uint2*)(sX + t * 256 + ((8 * cq) ^ fsw(t))) = pk;
        }
    }
    __syncthreads();   // THE ONLY BARRIER

    bf16x4 fQ[4][2], fK[4][2], fV[4][2];

    // ---- K then Q projection (W.X^T): D[och 4lg+r][tok lr] ----
    #pragma unroll 1
    for (int p = 0; p < 2; ++p) {
        const ushort* wp = wbf + (p == 0 ? 16384 : 0);
        const float* bias_p = (p == 0) ? bk : bq;
        f32x4 acc[2][4];   // [tn][tm]
        #pragma unroll
        for (int tn = 0; tn < 2; ++tn) {
            float4 bb = *(const float4*)(bias_p + 32 * w + 16 * tn + 4 * lg);
            #pragma unroll
            for (int tm = 0; tm < 4; ++tm)
                acc[tn][tm] = (f32x4){bb.x, bb.y, bb.z, bb.w};
        }
        #pragma unroll
        for (int kk = 0; kk < 4; ++kk) {
            bf16x8 aXk[4];
            #pragma unroll
            for (int tm = 0; tm < 4; ++tm) {
                int row = 16 * tm + lr;
                aXk[tm] = *(const bf16x8*)(sX + row * 256
                              + (((8 * lg + 32 * kk) * 2) ^ fsw(row)));
            }
            bf16x8 bW[2];
            #pragma unroll
            for (int tn = 0; tn < 2; ++tn)
                bW[tn] = *(const bf16x8*)(wp + (32 * w + 16 * tn + lr) * 128 + 8 * lg + 32 * kk);
            #pragma unroll
            for (int tn = 0; tn < 2; ++tn)
                #pragma unroll
                for (int tm = 0; tm < 4; ++tm)
                    acc[tn][tm] = MFMA32(bW[tn], aXk[tm], acc[tn][tm]);
        }
        #pragma unroll
        for (int tm = 0; tm < 4; ++tm)
            #pragma unroll
            for (int tn = 0; tn < 2; ++tn) {
                bf16x4 f = pk4(acc[tn][tm][0], acc[tn][tm][1],
                               acc[tn][tm][2], acc[tn][tm][3]);
                if (p == 0) fK[tm][tn] = f; else fQ[tm][tn] = f;
            }
    }

    // ---- V projection (X.W^T) in TWO och-half passes: acc 16 regs ----
    #pragma unroll 1
    for (int tn = 0; tn < 2; ++tn) {
        const ushort* wp = wbf + 32768;
        f32x4 acc[4];
        float bias = bv[32 * w + 16 * tn + lr];
        #pragma unroll
        for (int tmi = 0; tmi < 4; ++tmi)
            acc[tmi] = (f32x4){bias, bias, bias, bias};
        #pragma unroll
        for (int kk = 0; kk < 4; ++kk) {
            bf16x8 aXk[4];
            #pragma unroll
            for (int tmi = 0; tmi < 4; ++tmi) {
                int row = 16 * tmi + lr;
                aXk[tmi] = *(const bf16x8*)(sX + row * 256
                               + (((8 * lg + 32 * kk) * 2) ^ fsw(row)));
            }
            bf16x8 bW = *(const bf16x8*)(wp + (32 * w + 16 * tn + lr) * 128 + 8 * lg + 32 * kk);
            #pragma unroll
            for (int tmi = 0; tmi < 4; ++tmi)
                acc[tmi] = MFMA32(aXk[tmi], bW, acc[tmi]);
        }
        #pragma unroll
        for (int tmi = 0; tmi < 4; ++tmi)
            fV[tmi][tn] = pk4(acc[tmi][0], acc[tmi][1], acc[tmi][2], acc[tmi][3]);
    }

    // ---- attention per tmQ column: full sc -> s -> normalize-pack -> PV ----
    const float scale = 0.17677669529663687f;   // 1/sqrt(32)
    const float L2E = 1.4426950408889634f;
    #pragma unroll 1
    for (int tmQ = 0; tmQ < 4; ++tmQ) {
        int q = 16 * tmQ + lr;
        f32x4 sc[4];
        #pragma unroll
        for (int tmK = 0; tmK < 4; ++tmK) {
            sc[tmK] = (f32x4){0.f, 0.f, 0.f, 0.f};
            sc[tmK] = MFMA16(fK[tmK][0], fQ[tmQ][0], sc[tmK]);
            sc[tmK] = MFMA16(fK[tmK][1], fQ[tmQ][1], sc[tmK]);
        }
        float s = 0.f;
        #pragma unroll
        for (int tmK = 0; tmK < 4; ++tmK) {
            float4 bb = *(const float4*)(Bb + q * 64 + 16 * tmK + 4 * lg);
            float e0 = exp2f((sc[tmK][0] * scale + bb.x) * L2E);
            float e1 = exp2f((sc[tmK][1] * scale + bb.y) * L2E);
            float e2 = exp2f((sc[tmK][2] * scale + bb.z) * L2E);
            float e3 = exp2f((sc[tmK][3] * scale + bb.w) * L2E);
            sc[tmK][0] = e0; sc[tmK][1] = e1;
            sc[tmK][2] = e2; sc[tmK][3] = e3;
            s += (e0 + e1) + (e2 + e3);
        }
        s += __shfl_xor(s, 16);
        s += __shfl_xor(s, 32);
        float rs = 1.0f / s;
        f32x4 o0 = (f32x4){0.f, 0.f, 0.f, 0.f};
        f32x4 o1 = (f32x4){0.f, 0.f, 0.f, 0.f};
        #pragma unroll
        for (int tmK = 0; tmK < 4; ++tmK) {
            bf16x4 pk = pk4(sc[tmK][0] * rs, sc[tmK][1] * rs,
                            sc[tmK][2] * rs, sc[tmK][3] * rs);
            o0 = MFMA16(pk, fV[tmK][0], o0);
            o1 = MFMA16(pk, fV[tmK][1], o1);
        }
        // stores: tok = 16tmQ + 4lg + r, ch = 32w + 16tn + lr
        {
            int ch = 32 * w + lr;
            int tok = 16 * tmQ + 4 * lg;
            float4 ov;
            ov.x = o0[0]; ov.y = o0[1]; ov.z = o0[2]; ov.w = o0[3];
            *(float4*)(out + xbase + (long)ch * 16384 + tok) = ov;
            float4 ov1;
            ov1.x = o1[0]; ov1.y = o1[1]; ov1.z = o1[2]; ov1.w = o1[3];
            *(float4*)(out + xbase + (long)(ch + 16) * 16384 + tok) = ov1;
        }
    }
}

extern "C" void kernel_launch(void* const* d_in, const int* in_sizes, int n_in,
                              void* d_out, int out_size, void* d_ws, size_t ws_size,
                              hipStream_t stream) {
    const float* x  = (const float*)d_in[0];
    const float* Wq = (const float*)d_in[1];
    const float* bq = (const float*)d_in[2];
    const float* Wk = (const float*)d_in[3];
    const float* bk = (const float*)d_in[4];
    const float* Wv = (const float*)d_in[5];
    const float* bv = (const float*)d_in[6];
    const float* Bb = (const float*)d_in[7];
    float* out = (float*)d_out;
    ushort* wbf = (ushort*)d_ws;   // 3 x 128x128 bf16 = 96 KB

    wconv<<<64, 256, 0, stream>>>(Wq, Wk, Wv, wbf);
    attn_win<<<4096, 256, 0, stream>>>(x, wbf, bq, bk, bv, Bb, out);
}

// Round 26
// 177.971 us; speedup vs baseline: 1.3192x; 1.0173x over previous
//
#include <hip/hip_runtime.h>
#include <hip/hip_bf16.h>

// Windowed MHA, B=16 C=128 H=W=128, WINDOW=64, heads=4, d=32.
// R26 = R20 pipeline, TWO windows per 256-thr block (grid 2048):
//   stage window A AND window B up-front (direct load->pack->ds_write,
//   transient regs only -- NOT R16/R21's held-register prefetch that
//   spilled) -> ONE barrier -> compute A then B (byte-identical R20).
// Window B: zero staging stall, L1-hot weights; cold starts halved.
// LDS 32KB. Register profile identical to R20 (~76 VGPR).

typedef __attribute__((ext_vector_type(8))) short bf16x8;
typedef __attribute__((ext_vector_type(4))) short bf16x4;
typedef __attribute__((ext_vector_type(4))) float f32x4;

#define MFMA32(A, B, C) __builtin_amdgcn_mfma_f32_16x16x32_bf16((A), (B), (C), 0, 0, 0)
#define MFMA16(A, B, C) __builtin_amdgcn_mfma_f32_16x16x16bf16_1k((A), (B), (C), 0, 0, 0)

__device__ __forceinline__ ushort f2bf(float f) {
    __hip_bfloat16 h = __float2bfloat16(f);       // RNE
    ushort u; __builtin_memcpy(&u, &h, 2); return u;
}
__device__ __forceinline__ unsigned pk2(float a, float b) {
    __hip_bfloat162 h = __float22bfloat162_rn(make_float2(a, b));  // lo=a, hi=b
    unsigned u; __builtin_memcpy(&u, &h, 4); return u;
}
__device__ __forceinline__ bf16x4 pk4(float a, float b, float c, float d) {
    uint2 u; u.x = pk2(a, b); u.y = pk2(c, d);
    bf16x4 r; __builtin_memcpy(&r, &u, 8); return r;
}
// 256B-row tile (sX): row bits 0-3 ^ bits 4-5 -> byte bits 4-7.
__device__ __forceinline__ int fsw(int row) { return ((row ^ (row >> 4)) & 15) << 4; }

__global__ void wconv(const float* __restrict__ Wq, const float* __restrict__ Wk,
                      const float* __restrict__ Wv, ushort* __restrict__ out) {
    int i = blockIdx.x * 256 + threadIdx.x;        // 16384 per matrix
    out[i]         = f2bf(Wq[i]);
    out[16384 + i] = f2bf(Wk[i]);
    out[32768 + i] = f2bf(Wv[i]);
}

__global__ __launch_bounds__(256, 2)
void attn_win(const float* __restrict__ x, const ushort* __restrict__ wbf,
              const float* __restrict__ bq, const float* __restrict__ bk,
              const float* __restrict__ bv, const float* __restrict__ Bb,
              float* __restrict__ out) {
    __shared__ __align__(16) char sX[2][16384];

    const int tid = threadIdx.x;
    const int w = tid >> 6;          // wave = head (0..3)
    const int l = tid & 63;
    const int lr = l & 15;
    const int lg = (l >> 4) & 3;
    const int blk = blockIdx.x;      // 2048 blocks; windows 2blk, 2blk+1
    const int gw0 = 2 * blk;         // even -> both windows share batch b
    const long xbase0 = (long)(gw0 >> 8) * 128 * 16384 + (long)(gw0 & 255) * 64;

    // ---- stage BOTH windows: direct load -> pack -> ds_write (transient) ----
    #pragma unroll
    for (int it = 0; it < 4; ++it) {
        int idx = it * 256 + tid;            // 1024 items: swi x 32cq x 16t4
        int swi = idx >> 9, rem = idx & 511;
        int cq = rem >> 4, t4 = rem & 15;
        const float* px = x + xbase0 + swi * 64 + (long)(4 * cq) * 16384 + t4 * 4;
        float4 v0 = *(const float4*)(px);
        float4 v1 = *(const float4*)(px + 16384);
        float4 v2 = *(const float4*)(px + 32768);
        float4 v3 = *(const float4*)(px + 49152);
        float a0[4] = {v0.x, v0.y, v0.z, v0.w};
        float a1[4] = {v1.x, v1.y, v1.z, v1.w};
        float a2[4] = {v2.x, v2.y, v2.z, v2.w};
        float a3[4] = {v3.x, v3.y, v3.z, v3.w};
        #pragma unroll
        for (int jj = 0; jj < 4; ++jj) {
            int t = t4 * 4 + jj;
            uint2 pk;
            pk.x = pk2(a0[jj], a1[jj]);
            pk.y = pk2(a2[jj], a3[jj]);
            *(uint2*)(&sX[swi][0] + t * 256 + ((8 * cq) ^ fsw(t))) = pk;
        }
    }
    __syncthreads();   // THE ONLY BARRIER

    #pragma unroll 1
    for (int wi = 0; wi < 2; ++wi) {
        const char* sXw = &sX[wi][0];
        const long xb = xbase0 + wi * 64;

        // ---- Q,K,V projections fused, K=32 MFMA (R20) ----
        bf16x4 fQ[4][2], fK[4][2], fV[4][2];
        {
            f32x4 accQ[2][4], accK[2][4], accV[4][2];
            #pragma unroll
            for (int tn = 0; tn < 2; ++tn) {
                float4 bbq = *(const float4*)(bq + 32 * w + 16 * tn + 4 * lg);
                float4 bbk = *(const float4*)(bk + 32 * w + 16 * tn + 4 * lg);
                float bvv = bv[32 * w + 16 * tn + lr];
                #pragma unroll
                for (int tm = 0; tm < 4; ++tm) {
                    accQ[tn][tm] = (f32x4){bbq.x, bbq.y, bbq.z, bbq.w};
                    accK[tn][tm] = (f32x4){bbk.x, bbk.y, bbk.z, bbk.w};
                    accV[tm][tn] = (f32x4){bvv, bvv, bvv, bvv};
                }
            }
            #pragma unroll
            for (int kk = 0; kk < 4; ++kk) {
                bf16x8 aXk[4];
                #pragma unroll
                for (int tm = 0; tm < 4; ++tm) {
                    int row = 16 * tm + lr;
                    aXk[tm] = *(const bf16x8*)(sXw + row * 256
                                  + (((8 * lg + 32 * kk) * 2) ^ fsw(row)));
                }
                bf16x8 bWq[2], bWk[2], bWv[2];
                #pragma unroll
                for (int tn = 0; tn < 2; ++tn) {
                    int orow = (32 * w + 16 * tn + lr) * 128 + 8 * lg + 32 * kk;
                    bWq[tn] = *(const bf16x8*)(wbf + orow);
                    bWk[tn] = *(const bf16x8*)(wbf + 16384 + orow);
                    bWv[tn] = *(const bf16x8*)(wbf + 32768 + orow);
                }
                #pragma unroll
                for (int tn = 0; tn < 2; ++tn)
                    #pragma unroll
                    for (int tm = 0; tm < 4; ++tm) {
                        accQ[tn][tm] = MFMA32(bWq[tn], aXk[tm], accQ[tn][tm]);
                        accK[tn][tm] = MFMA32(bWk[tn], aXk[tm], accK[tn][tm]);
                        accV[tm][tn] = MFMA32(aXk[tm], bWv[tn], accV[tm][tn]);
                    }
            }
            #pragma unroll
            for (int tm = 0; tm < 4; ++tm)
                #pragma unroll
                for (int tn = 0; tn < 2; ++tn) {
                    fQ[tm][tn] = pk4(accQ[tn][tm][0], accQ[tn][tm][1],
                                     accQ[tn][tm][2], accQ[tn][tm][3]);
                    fK[tm][tn] = pk4(accK[tn][tm][0], accK[tn][tm][1],
                                     accK[tn][tm][2], accK[tn][tm][3]);
                    fV[tm][tn] = pk4(accV[tm][tn][0], accV[tm][tn][1],
                                     accV[tm][tn][2], accV[tm][tn][3]);
                }
        }

        // ---- per-tmQ: scores^T (K=16) -> softmax -> pack P (R18/R20) ----
        const float scale = 0.17677669529663687f;   // 1/sqrt(32)
        const float L2E = 1.4426950408889634f;
        bf16x4 pP[4][4];   // [tmK][tmQ]
        #pragma unroll
        for (int tmQ = 0; tmQ < 4; ++tmQ) {
            f32x4 sc[4];
            #pragma unroll
            for (int tmK = 0; tmK < 4; ++tmK) {
                sc[tmK] = (f32x4){0.f, 0.f, 0.f, 0.f};
                sc[tmK] = MFMA16(fK[tmK][0], fQ[tmQ][0], sc[tmK]);
                sc[tmK] = MFMA16(fK[tmK][1], fQ[tmQ][1], sc[tmK]);
            }
            int q = 16 * tmQ + lr;
            float s = 0.f;
            #pragma unroll
            for (int tmK = 0; tmK < 4; ++tmK) {
                float4 bb = *(const float4*)(Bb + q * 64 + 16 * tmK + 4 * lg);
                float e0 = exp2f((sc[tmK][0] * scale + bb.x) * L2E);
                float e1 = exp2f((sc[tmK][1] * scale + bb.y) * L2E);
                float e2 = exp2f((sc[tmK][2] * scale + bb.z) * L2E);
                float e3 = exp2f((sc[tmK][3] * scale + bb.w) * L2E);
                sc[tmK][0] = e0; sc[tmK][1] = e1;
                sc[tmK][2] = e2; sc[tmK][3] = e3;
                s += (e0 + e1) + (e2 + e3);
            }
            s += __shfl_xor(s, 16);
            s += __shfl_xor(s, 32);
            float rs = 1.0f / s;
            #pragma unroll
            for (int tmK = 0; tmK < 4; ++tmK)
                pP[tmK][tmQ] = pk4(sc[tmK][0] * rs, sc[tmK][1] * rs,
                                   sc[tmK][2] * rs, sc[tmK][3] * rs);
        }

        // ---- PV: K=16 mfma(A=pP, B=fV); D[q 4lg+r][d lr] ----
        f32x4 o[4][2];
        #pragma unroll
        for (int tmq = 0; tmq < 4; ++tmq)
            #pragma unroll
            for (int tn = 0; tn < 2; ++tn)
                o[tmq][tn] = (f32x4){0.f, 0.f, 0.f, 0.f};
        #pragma unroll
        for (int tmK = 0; tmK < 4; ++tmK)
            #pragma unroll
            for (int tmq = 0; tmq < 4; ++tmq)
                #pragma unroll
                for (int tn = 0; tn < 2; ++tn)
                    o[tmq][tn] = MFMA16(pP[tmK][tmq], fV[tmK][tn], o[tmq][tn]);

        // ---- direct coalesced float4 stores ----
        #pragma unroll
        for (int tmq = 0; tmq < 4; ++tmq)
            #pragma unroll
            for (int tn = 0; tn < 2; ++tn) {
                int ch = 32 * w + 16 * tn + lr;
                int tok = 16 * tmq + 4 * lg;
                float4 ov;
                ov.x = o[tmq][tn][0];
                ov.y = o[tmq][tn][1];
                ov.z = o[tmq][tn][2];
                ov.w = o[tmq][tn][3];
                *(float4*)(out + xb + (long)ch * 16384 + tok) = ov;
            }
    }
}

extern "C" void kernel_launch(void* const* d_in, const int* in_sizes, int n_in,
                              void* d_out, int out_size, void* d_ws, size_t ws_size,
                              hipStream_t stream) {
    const float* x  = (const float*)d_in[0];
    const float* Wq = (const float*)d_in[1];
    const float* bq = (const float*)d_in[2];
    const float* Wk = (const float*)d_in[3];
    const float* bk = (const float*)d_in[4];
    const float* Wv = (const float*)d_in[5];
    const float* bv = (const float*)d_in[6];
    const float* Bb = (const float*)d_in[7];
    float* out = (float*)d_out;
    ushort* wbf = (ushort*)d_ws;   // 3 x 128x128 bf16 = 96 KB

    wconv<<<64, 256, 0, stream>>>(Wq, Wk, Wv, wbf);
    attn_win<<<2048, 256, 0, stream>>>(x, wbf, bq, bk, bv, Bb, out);
}

// Round 27
// 111.567 us; speedup vs baseline: 2.1043x; 1.5952x over previous
//
#include <hip/hip_runtime.h>
#include <hip/hip_bf16.h>

// Windowed MHA, B=16 C=128 H=W=128, WINDOW=64, heads=4, d=32.
// FINAL (R20, best measured: 111.5 us):
//  - one wave = one (window, head); 4096 blocks x 256 threads; ONE barrier
//  - X staged once to LDS (16KB, fsw-swizzled, conflict-free)
//  - Q/K/V projections fused in one kk loop, K=32 MFMA, b128 loads
//  - attention (QK^T, PV) in K=16 MFMA consuming the projection/softmax
//    D-layouts DIRECTLY (K=16 fragment k-map == D-layout reg-map) -> zero
//    cross-lane redistribution, zero associated bank conflicts
//  - softmax in registers (no max-sub: |scores| bounded ~0.5), normalized
//    before bf16 pack (abs err ~3e-5)
//  - direct coalesced float4 stores (4 consecutive tokens per acc reg)

typedef __attribute__((ext_vector_type(8))) short bf16x8;
typedef __attribute__((ext_vector_type(4))) short bf16x4;
typedef __attribute__((ext_vector_type(4))) float f32x4;

#define MFMA32(A, B, C) __builtin_amdgcn_mfma_f32_16x16x32_bf16((A), (B), (C), 0, 0, 0)
#define MFMA16(A, B, C) __builtin_amdgcn_mfma_f32_16x16x16bf16_1k((A), (B), (C), 0, 0, 0)

__device__ __forceinline__ ushort f2bf(float f) {
    __hip_bfloat16 h = __float2bfloat16(f);       // RNE
    ushort u; __builtin_memcpy(&u, &h, 2); return u;
}
__device__ __forceinline__ unsigned pk2(float a, float b) {
    __hip_bfloat162 h = __float22bfloat162_rn(make_float2(a, b));  // lo=a, hi=b
    unsigned u; __builtin_memcpy(&u, &h, 4); return u;
}
__device__ __forceinline__ bf16x4 pk4(float a, float b, float c, float d) {
    uint2 u; u.x = pk2(a, b); u.y = pk2(c, d);
    bf16x4 r; __builtin_memcpy(&r, &u, 8); return r;
}
// 256B-row tile (sX): row bits 0-3 ^ bits 4-5 -> byte bits 4-7.
__device__ __forceinline__ int fsw(int row) { return ((row ^ (row >> 4)) & 15) << 4; }

__global__ void wconv(const float* __restrict__ Wq, const float* __restrict__ Wk,
                      const float* __restrict__ Wv, ushort* __restrict__ out) {
    int i = blockIdx.x * 256 + threadIdx.x;        // 16384 per matrix
    out[i]         = f2bf(Wq[i]);
    out[16384 + i] = f2bf(Wk[i]);
    out[32768 + i] = f2bf(Wv[i]);
}

__global__ __launch_bounds__(256, 2)
void attn_win(const float* __restrict__ x, const ushort* __restrict__ wbf,
              const float* __restrict__ bq, const float* __restrict__ bk,
              const float* __restrict__ bv, const float* __restrict__ Bb,
              float* __restrict__ out) {
    __shared__ __align__(16) char sX[16384];   // the ONLY LDS tenant

    const int tid = threadIdx.x;
    const int w = tid >> 6;          // wave = head (0..3)
    const int l = tid & 63;
    const int lr = l & 15;
    const int lg = (l >> 4) & 3;
    const int blk = blockIdx.x;
    const int b = blk >> 8, n = blk & 255;
    const long xbase = (long)b * 128 * 16384 + n * 64;

    // ---- stage X: 4-channel quads -> packed uint2 ds_writes (2 per thread) ----
    #pragma unroll
    for (int it = 0; it < 2; ++it) {
        int idx = it * 256 + tid;            // 512 items: 32 cq x 16 t4
        int cq = idx >> 4, t4 = idx & 15;
        const float* px = x + xbase + (long)(4 * cq) * 16384 + t4 * 4;
        float4 v0 = *(const float4*)(px);
        float4 v1 = *(const float4*)(px + 16384);
        float4 v2 = *(const float4*)(px + 32768);
        float4 v3 = *(const float4*)(px + 49152);
        float a0[4] = {v0.x, v0.y, v0.z, v0.w};
        float a1[4] = {v1.x, v1.y, v1.z, v1.w};
        float a2[4] = {v2.x, v2.y, v2.z, v2.w};
        float a3[4] = {v3.x, v3.y, v3.z, v3.w};
        #pragma unroll
        for (int jj = 0; jj < 4; ++jj) {
            int t = t4 * 4 + jj;
            uint2 pk;
            pk.x = pk2(a0[jj], a1[jj]);
            pk.y = pk2(a2[jj], a3[jj]);
            *(uint2*)(sX + t * 256 + ((8 * cq) ^ fsw(t))) = pk;
        }
    }
    __syncthreads();   // THE ONLY BARRIER

    // ---- Q,K,V projections FULLY FUSED, K=32 MFMA, one kk loop ----
    // Q,K: W.X^T -> D[och 4lg+r][tok lr]  (A=W, B=X)
    // V:   X.W^T -> D[tok 4lg+r][och lr]  (A=X, B=W)
    bf16x4 fQ[4][2], fK[4][2];   // [tm tok-tile][tn och-slice] K=16 frags
    bf16x4 fV[4][2];             // [tmi key-slice][tn]
    {
        f32x4 accQ[2][4], accK[2][4], accV[4][2];
        #pragma unroll
        for (int tn = 0; tn < 2; ++tn) {
            float4 bbq = *(const float4*)(bq + 32 * w + 16 * tn + 4 * lg);
            float4 bbk = *(const float4*)(bk + 32 * w + 16 * tn + 4 * lg);
            float bvv = bv[32 * w + 16 * tn + lr];
            #pragma unroll
            for (int tm = 0; tm < 4; ++tm) {
                accQ[tn][tm] = (f32x4){bbq.x, bbq.y, bbq.z, bbq.w};
                accK[tn][tm] = (f32x4){bbk.x, bbk.y, bbk.z, bbk.w};
                accV[tm][tn] = (f32x4){bvv, bvv, bvv, bvv};
            }
        }
        #pragma unroll
        for (int kk = 0; kk < 4; ++kk) {
            bf16x8 aXk[4];
            #pragma unroll
            for (int tm = 0; tm < 4; ++tm) {
                int row = 16 * tm + lr;
                aXk[tm] = *(const bf16x8*)(sX + row * 256
                              + (((8 * lg + 32 * kk) * 2) ^ fsw(row)));
            }
            bf16x8 bWq[2], bWk[2], bWv[2];
            #pragma unroll
            for (int tn = 0; tn < 2; ++tn) {
                int orow = (32 * w + 16 * tn + lr) * 128 + 8 * lg + 32 * kk;
                bWq[tn] = *(const bf16x8*)(wbf + orow);
                bWk[tn] = *(const bf16x8*)(wbf + 16384 + orow);
                bWv[tn] = *(const bf16x8*)(wbf + 32768 + orow);
            }
            #pragma unroll
            for (int tn = 0; tn < 2; ++tn)
                #pragma unroll
                for (int tm = 0; tm < 4; ++tm) {
                    accQ[tn][tm] = MFMA32(bWq[tn], aXk[tm], accQ[tn][tm]);
                    accK[tn][tm] = MFMA32(bWk[tn], aXk[tm], accK[tn][tm]);
                    accV[tm][tn] = MFMA32(aXk[tm], bWv[tn], accV[tm][tn]);
                }
        }
        #pragma unroll
        for (int tm = 0; tm < 4; ++tm)
            #pragma unroll
            for (int tn = 0; tn < 2; ++tn) {
                fQ[tm][tn] = pk4(accQ[tn][tm][0], accQ[tn][tm][1],
                                 accQ[tn][tm][2], accQ[tn][tm][3]);
                fK[tm][tn] = pk4(accK[tn][tm][0], accK[tn][tm][1],
                                 accK[tn][tm][2], accK[tn][tm][3]);
                fV[tm][tn] = pk4(accV[tm][tn][0], accV[tm][tn][1],
                                 accV[tm][tn][2], accV[tm][tn][3]);
            }
    }

    // ---- per-tmQ: scores^T = K=16 mfma(A=fK, B=fQ) -> softmax -> pack P ----
    // D[k 16tmK+4lg+r][q 16tmQ+lr]; P pack is directly the PV A-fragment.
    const float scale = 0.17677669529663687f;   // 1/sqrt(32)
    const float L2E = 1.4426950408889634f;
    bf16x4 pP[4][4];   // [tmK][tmQ]
    #pragma unroll
    for (int tmQ = 0; tmQ < 4; ++tmQ) {
        f32x4 sc[4];
        #pragma unroll
        for (int tmK = 0; tmK < 4; ++tmK) {
            sc[tmK] = (f32x4){0.f, 0.f, 0.f, 0.f};
            sc[tmK] = MFMA16(fK[tmK][0], fQ[tmQ][0], sc[tmK]);
            sc[tmK] = MFMA16(fK[tmK][1], fQ[tmQ][1], sc[tmK]);
        }
        int q = 16 * tmQ + lr;
        float s = 0.f;
        #pragma unroll
        for (int tmK = 0; tmK < 4; ++tmK) {
            float4 bb = *(const float4*)(Bb + q * 64 + 16 * tmK + 4 * lg);
            float e0 = exp2f((sc[tmK][0] * scale + bb.x) * L2E);
            float e1 = exp2f((sc[tmK][1] * scale + bb.y) * L2E);
            float e2 = exp2f((sc[tmK][2] * scale + bb.z) * L2E);
            float e3 = exp2f((sc[tmK][3] * scale + bb.w) * L2E);
            sc[tmK][0] = e0; sc[tmK][1] = e1;
            sc[tmK][2] = e2; sc[tmK][3] = e3;
            s += (e0 + e1) + (e2 + e3);
        }
        s += __shfl_xor(s, 16);
        s += __shfl_xor(s, 32);
        float rs = 1.0f / s;
        #pragma unroll
        for (int tmK = 0; tmK < 4; ++tmK)
            pP[tmK][tmQ] = pk4(sc[tmK][0] * rs, sc[tmK][1] * rs,
                               sc[tmK][2] * rs, sc[tmK][3] * rs);
    }

    // ---- PV: K=16 mfma(A=pP, B=fV); D[q 4lg+r][d lr] ----
    f32x4 o[4][2];
    #pragma unroll
    for (int tmq = 0; tmq < 4; ++tmq)
        #pragma unroll
        for (int tn = 0; tn < 2; ++tn)
            o[tmq][tn] = (f32x4){0.f, 0.f, 0.f, 0.f};
    #pragma unroll
    for (int tmK = 0; tmK < 4; ++tmK)
        #pragma unroll
        for (int tmq = 0; tmq < 4; ++tmq)
            #pragma unroll
            for (int tn = 0; tn < 2; ++tn)
                o[tmq][tn] = MFMA16(pP[tmK][tmq], fV[tmK][tn], o[tmq][tn]);

    // ---- direct coalesced float4 stores (4 consecutive tokens per reg) ----
    #pragma unroll
    for (int tmq = 0; tmq < 4; ++tmq)
        #pragma unroll
        for (int tn = 0; tn < 2; ++tn) {
            int ch = 32 * w + 16 * tn + lr;
            int tok = 16 * tmq + 4 * lg;
            float4 ov;
            ov.x = o[tmq][tn][0];
            ov.y = o[tmq][tn][1];
            ov.z = o[tmq][tn][2];
            ov.w = o[tmq][tn][3];
            *(float4*)(out + xbase + (long)ch * 16384 + tok) = ov;
        }
}

extern "C" void kernel_launch(void* const* d_in, const int* in_sizes, int n_in,
                              void* d_out, int out_size, void* d_ws, size_t ws_size,
                              hipStream_t stream) {
    const float* x  = (const float*)d_in[0];
    const float* Wq = (const float*)d_in[1];
    const float* bq = (const float*)d_in[2];
    const float* Wk = (const float*)d_in[3];
    const float* bk = (const float*)d_in[4];
    const float* Wv = (const float*)d_in[5];
    const float* bv = (const float*)d_in[6];
    const float* Bb = (const float*)d_in[7];
    float* out = (float*)d_out;
    ushort* wbf = (ushort*)d_ws;   // 3 x 128x128 bf16 = 96 KB

    wconv<<<64, 256, 0, stream>>>(Wq, Wk, Wv, wbf);
    attn_win<<<4096, 256, 0, stream>>>(x, wbf, bq, bk, bv, Bb, out);
}